// Round 1
// baseline (623.158 us; speedup 1.0000x reference)
//
#include <hip/hip_runtime.h>
#include <hip/hip_bf16.h>

#define NN 50000
#define EE 800000

__device__ __forceinline__ float lrelu(float x, float s){ return x > 0.f ? x : x * s; }

// ---------------- CSR build ----------------

// Decide whether edge_index is int64 (odd 32-bit words all zero) or int32.
__global__ void detect_kernel(const int* __restrict__ ei, int* __restrict__ flag){
  __shared__ int any;
  if (threadIdx.x == 0) any = 0;
  __syncthreads();
  if (ei[2 * threadIdx.x + 1] != 0) atomicOr(&any, 1);
  __syncthreads();
  if (threadIdx.x == 0) *flag = (any == 0) ? 1 : 0;
}

__global__ void zero2_kernel(int* __restrict__ a, int* __restrict__ b, int n){
  int i = blockIdx.x * blockDim.x + threadIdx.x;
  if (i < n){ a[i] = 0; b[i] = 0; }
}

__global__ void count_kernel(const int* __restrict__ ei, const int* __restrict__ flag,
                             int* __restrict__ deg){
  int e = blockIdx.x * blockDim.x + threadIdx.x;
  if (e >= EE) return;
  int f = *flag;
  int d = f ? ei[2 * (EE + e)] : ei[EE + e];
  atomicAdd(&deg[d], 1);
}

__global__ void scan_kernel(const int* __restrict__ deg, int* __restrict__ rowptr){
  __shared__ int tmp[1024];
  __shared__ int carry_s;
  int tid = threadIdx.x;
  if (tid == 0) carry_s = 0;
  __syncthreads();
  for (int base = 0; base < NN; base += 1024){
    int idx = base + tid;
    int v = (idx < NN) ? deg[idx] : 0;
    tmp[tid] = v;
    __syncthreads();
    for (int off = 1; off < 1024; off <<= 1){
      int t = (tid >= off) ? tmp[tid - off] : 0;
      __syncthreads();
      tmp[tid] += t;
      __syncthreads();
    }
    if (idx < NN) rowptr[idx] = carry_s + tmp[tid] - v;   // exclusive scan
    __syncthreads();
    if (tid == 0) carry_s += tmp[1023];
    __syncthreads();
  }
  if (tid == 0) rowptr[NN] = carry_s;
}

__global__ void scatter_kernel(const int* __restrict__ ei, const int* __restrict__ flag,
                               const int* __restrict__ rowptr, int* __restrict__ cursor,
                               int* __restrict__ csr_src){
  int e = blockIdx.x * blockDim.x + threadIdx.x;
  if (e >= EE) return;
  int f = *flag;
  int s = f ? ei[2 * e] : ei[e];
  int d = f ? ei[2 * (EE + e)] : ei[EE + e];
  int pos = atomicAdd(&cursor[d], 1);
  csr_src[rowptr[d] + pos] = s;
}

// ---------------- fused SGEMM ----------------
// out[r][c] = epilogue( sum_k A[r][k]*W[k][c] )
// EPI: 0 = +bias ; 1 = +bias, BN, leaky(0.1) ; 2 = +bias, leaky(0.1)
template<int KIN, int KOUT, int EPI>
__launch_bounds__(256)
__global__ void gemm_kernel(const float* __restrict__ A, const float* __restrict__ W,
                            const float* __restrict__ bias,
                            const float* __restrict__ bn_g, const float* __restrict__ bn_b,
                            const float* __restrict__ bn_m, const float* __restrict__ bn_v,
                            float* __restrict__ out, int n){
  constexpr int CG  = KOUT / 8;     // col-groups (each thread owns 2 float4 col blocks)
  constexpr int RG  = 256 / CG;     // row-groups
  constexpr int RPT = 128 / RG;     // rows per thread
  constexpr int SAS = KIN + 4;      // padded A stride (breaks bank aliasing across rows)
  constexpr int SWS = KOUT;         // W stride (reads are >=2-way-free by construction)
  __shared__ float sA[128 * SAS];
  __shared__ float sW[KIN * SWS];
  const int tid = threadIdx.x;
  const long r0 = (long)blockIdx.x * 128;

  for (int idx = tid; idx < KIN * KOUT / 4; idx += 256){
    float4 w = reinterpret_cast<const float4*>(W)[idx];
    int k = idx / (KOUT / 4), c4 = idx % (KOUT / 4);
    *reinterpret_cast<float4*>(&sW[k * SWS + c4 * 4]) = w;
  }
  for (int idx = tid; idx < 128 * (KIN / 4); idx += 256){
    int r = idx / (KIN / 4), k4 = idx % (KIN / 4);
    float4 a = make_float4(0.f, 0.f, 0.f, 0.f);
    if (r0 + r < n) a = reinterpret_cast<const float4*>(A)[(r0 + r) * (KIN / 4) + k4];
    *reinterpret_cast<float4*>(&sA[r * SAS + k4 * 4]) = a;
  }
  __syncthreads();

  const int tr = tid / CG;            // 0..RG-1  (rows tr + RG*i)
  const int tc = tid % CG;            // 0..CG-1
  const int c0 = tc * 4;              // first float4 col block
  const int c1 = KOUT / 2 + tc * 4;   // second float4 col block

  float acc[RPT][8];
  #pragma unroll
  for (int i = 0; i < RPT; i++)
    #pragma unroll
    for (int j = 0; j < 8; j++) acc[i][j] = 0.f;

  for (int k = 0; k < KIN; k += 4){
    float4 a4[RPT];
    #pragma unroll
    for (int i = 0; i < RPT; i++)
      a4[i] = *reinterpret_cast<const float4*>(&sA[(tr + RG * i) * SAS + k]);
    #pragma unroll
    for (int kk = 0; kk < 4; kk++){
      float4 w0 = *reinterpret_cast<const float4*>(&sW[(k + kk) * SWS + c0]);
      float4 w1 = *reinterpret_cast<const float4*>(&sW[(k + kk) * SWS + c1]);
      #pragma unroll
      for (int i = 0; i < RPT; i++){
        float av = (kk == 0) ? a4[i].x : (kk == 1) ? a4[i].y : (kk == 2) ? a4[i].z : a4[i].w;
        acc[i][0] = fmaf(av, w0.x, acc[i][0]);
        acc[i][1] = fmaf(av, w0.y, acc[i][1]);
        acc[i][2] = fmaf(av, w0.z, acc[i][2]);
        acc[i][3] = fmaf(av, w0.w, acc[i][3]);
        acc[i][4] = fmaf(av, w1.x, acc[i][4]);
        acc[i][5] = fmaf(av, w1.y, acc[i][5]);
        acc[i][6] = fmaf(av, w1.z, acc[i][6]);
        acc[i][7] = fmaf(av, w1.w, acc[i][7]);
      }
    }
  }

  float cb[8], cg_[8], cbb[8], cm[8], cv[8];
  #pragma unroll
  for (int j = 0; j < 8; j++){
    int c = (j < 4) ? (c0 + j) : (c1 + j - 4);
    cb[j] = bias[c];
    if (EPI == 1){ cg_[j] = bn_g[c]; cbb[j] = bn_b[c]; cm[j] = bn_m[c]; cv[j] = bn_v[c]; }
  }
  #pragma unroll
  for (int i = 0; i < RPT; i++){
    long r = r0 + tr + RG * i;
    if (r < n){
      float vv[8];
      #pragma unroll
      for (int j = 0; j < 8; j++){
        float v = acc[i][j] + cb[j];
        if (EPI == 1){
          v = (v - cm[j]) * rsqrtf(cv[j] + 1e-5f) * cg_[j] + cbb[j];
          v = lrelu(v, 0.1f);
        }
        if (EPI == 2){ v = lrelu(v, 0.1f); }
        vv[j] = v;
      }
      *reinterpret_cast<float4*>(&out[r * KOUT + c0]) = make_float4(vv[0], vv[1], vv[2], vv[3]);
      *reinterpret_cast<float4*>(&out[r * KOUT + c1]) = make_float4(vv[4], vv[5], vv[6], vv[7]);
    }
  }
}

// ---------------- GATv2 edge phase (one wave per dst node, online softmax) ----------------
// lane l owns channels l and l+64. Heads: head(ch)=ch>>5, so the 32-lane halves
// reduce exactly one head per partial. Fused epilogue: /den, +bias, BN, leaky(0.1), +H.
// OUT may alias XR (only node d's wave touches row d of XR).
__global__ void gat_edge_kernel(const float* __restrict__ XL, const float* __restrict__ XR,
                                const float* __restrict__ att, const float* __restrict__ bias,
                                const float* __restrict__ bn_g, const float* __restrict__ bn_b,
                                const float* __restrict__ bn_m, const float* __restrict__ bn_v,
                                const float* __restrict__ H, float* __restrict__ OUT,
                                const int* __restrict__ rowptr, const int* __restrict__ csr_src,
                                int n){
  int wid  = (int)((blockIdx.x * blockDim.x + threadIdx.x) >> 6);
  int lane = threadIdx.x & 63;
  if (wid >= n) return;
  const int d = wid;
  const int ch0 = lane, ch1 = lane + 64;
  const float a0 = att[ch0], a1 = att[ch1];
  const float xr0 = XR[(long)d * 128 + ch0];
  const float xr1 = XR[(long)d * 128 + ch1];
  const float xd0 = XL[(long)d * 128 + ch0];
  const float xd1 = XL[(long)d * 128 + ch1];

  // self loop first
  float p0 = lrelu(xr0 + xd0, 0.2f) * a0;
  float p1 = lrelu(xr1 + xd1, 0.2f) * a1;
  #pragma unroll
  for (int off = 1; off < 32; off <<= 1){ p0 += __shfl_xor(p0, off); p1 += __shfl_xor(p1, off); }
  float m0 = p0, m1 = p1;
  float den0 = 1.f, den1 = 1.f;
  float O0 = xd0, O1 = xd1;

  const int start = rowptr[d], end = rowptr[d + 1];
  float nxs0 = 0.f, nxs1 = 0.f;
  if (start < end){
    int si = csr_src[start];
    nxs0 = XL[(long)si * 128 + ch0];
    nxs1 = XL[(long)si * 128 + ch1];
  }
  for (int e = start; e < end; e++){
    float xs0 = nxs0, xs1 = nxs1;
    if (e + 1 < end){
      int si = csr_src[e + 1];
      nxs0 = XL[(long)si * 128 + ch0];
      nxs1 = XL[(long)si * 128 + ch1];
    }
    float l0 = lrelu(xr0 + xs0, 0.2f) * a0;
    float l1 = lrelu(xr1 + xs1, 0.2f) * a1;
    #pragma unroll
    for (int off = 1; off < 32; off <<= 1){ l0 += __shfl_xor(l0, off); l1 += __shfl_xor(l1, off); }
    float nm0 = fmaxf(m0, l0); float sc0 = __expf(m0 - nm0); float w0 = __expf(l0 - nm0);
    den0 = den0 * sc0 + w0; O0 = O0 * sc0 + w0 * xs0; m0 = nm0;
    float nm1 = fmaxf(m1, l1); float sc1 = __expf(m1 - nm1); float w1 = __expf(l1 - nm1);
    den1 = den1 * sc1 + w1; O1 = O1 * sc1 + w1 * xs1; m1 = nm1;
  }

  float v0 = O0 / (den0 + 1e-16f) + bias[ch0];
  float v1 = O1 / (den1 + 1e-16f) + bias[ch1];
  v0 = (v0 - bn_m[ch0]) * rsqrtf(bn_v[ch0] + 1e-5f) * bn_g[ch0] + bn_b[ch0];
  v1 = (v1 - bn_m[ch1]) * rsqrtf(bn_v[ch1] + 1e-5f) * bn_g[ch1] + bn_b[ch1];
  v0 = lrelu(v0, 0.1f) + H[(long)d * 128 + ch0];
  v1 = lrelu(v1, 0.1f) + H[(long)d * 128 + ch1];
  OUT[(long)d * 128 + ch0] = v0;
  OUT[(long)d * 128 + ch1] = v1;
}

// ---------------- final 64->1 projection ----------------
__global__ void out2_kernel(const float* __restrict__ Hin, const float* __restrict__ Wo2,
                            const float* __restrict__ bo2, float* __restrict__ out, int n){
  int wid  = (int)((blockIdx.x * blockDim.x + threadIdx.x) >> 6);
  int lane = threadIdx.x & 63;
  if (wid >= n) return;
  float p = Hin[(long)wid * 64 + lane] * Wo2[lane];
  #pragma unroll
  for (int off = 1; off < 64; off <<= 1) p += __shfl_xor(p, off);
  if (lane == 0) out[wid] = p + bo2[0];
}

// ---------------- launch ----------------
extern "C" void kernel_launch(void* const* d_in, const int* in_sizes, int n_in,
                              void* d_out, int out_size, void* d_ws, size_t ws_size,
                              hipStream_t stream) {
  const float* x     = (const float*)d_in[0];
  const int*   ei    = (const int*)  d_in[1];
  const float* W_pre = (const float*)d_in[2];
  const float* b_pre = (const float*)d_in[3];
  const float* g_pre = (const float*)d_in[4];
  const float* be_pre= (const float*)d_in[5];
  const float* m_pre = (const float*)d_in[6];
  const float* v_pre = (const float*)d_in[7];
  const float* Wl1  = (const float*)d_in[8];
  const float* bl1  = (const float*)d_in[9];
  const float* Wr1  = (const float*)d_in[10];
  const float* br1  = (const float*)d_in[11];
  const float* att1 = (const float*)d_in[12];
  const float* bias1= (const float*)d_in[13];
  const float* g1   = (const float*)d_in[14];
  const float* be1  = (const float*)d_in[15];
  const float* m1   = (const float*)d_in[16];
  const float* v1   = (const float*)d_in[17];
  const float* Wl2  = (const float*)d_in[18];
  const float* bl2  = (const float*)d_in[19];
  const float* Wr2  = (const float*)d_in[20];
  const float* br2  = (const float*)d_in[21];
  const float* att2 = (const float*)d_in[22];
  const float* bias2= (const float*)d_in[23];
  const float* g2   = (const float*)d_in[24];
  const float* be2  = (const float*)d_in[25];
  const float* m2   = (const float*)d_in[26];
  const float* v2   = (const float*)d_in[27];
  const float* Wo1  = (const float*)d_in[28];
  const float* bo1  = (const float*)d_in[29];
  const float* Wo2  = (const float*)d_in[30];
  const float* bo2  = (const float*)d_in[31];
  float* out = (float*)d_out;
  char*  ws  = (char*)d_ws;

  float* buf0 = (float*)(ws + 0);           // [N,128]
  float* buf1 = (float*)(ws + 25600000);    // [N,128]
  float* buf2 = (float*)(ws + 51200000);    // [N,128]
  int* rowptr = (int*)(ws + 76800000);      // N+1
  int* deg    = (int*)(ws + 77000448);      // N
  int* cursor = (int*)(ws + 77200448);      // N
  int* csr    = (int*)(ws + 77400448);      // E
  int* flag   = (int*)(ws + 80600448);      // 1

  // CSR build (reused by both GAT layers)
  detect_kernel<<<1, 256, 0, stream>>>(ei, flag);
  zero2_kernel<<<(NN + 255) / 256, 256, 0, stream>>>(deg, cursor, NN);
  count_kernel<<<(EE + 255) / 256, 256, 0, stream>>>(ei, flag, deg);
  scan_kernel<<<1, 1024, 0, stream>>>(deg, rowptr);
  scatter_kernel<<<(EE + 255) / 256, 256, 0, stream>>>(ei, flag, rowptr, cursor, csr);

  const int GG = (NN + 127) / 128;   // 391 GEMM blocks
  const int GW = (NN + 3) / 4;       // 12500 wave-per-node blocks

  // pre: x0 = leaky(BN(x@W_pre + b_pre)) -> buf0
  gemm_kernel<64, 128, 1><<<GG, 256, 0, stream>>>(x, W_pre, b_pre, g_pre, be_pre, m_pre, v_pre, buf0, NN);
  // layer 1
  gemm_kernel<128, 128, 0><<<GG, 256, 0, stream>>>(buf0, Wl1, bl1, nullptr, nullptr, nullptr, nullptr, buf1, NN);
  gemm_kernel<128, 128, 0><<<GG, 256, 0, stream>>>(buf0, Wr1, br1, nullptr, nullptr, nullptr, nullptr, buf2, NN);
  gat_edge_kernel<<<GW, 256, 0, stream>>>(buf1, buf2, att1, bias1, g1, be1, m1, v1,
                                          buf0 /*H*/, buf2 /*OUT in-place*/, rowptr, csr, NN);
  // layer 2
  gemm_kernel<128, 128, 0><<<GG, 256, 0, stream>>>(buf2, Wl2, bl2, nullptr, nullptr, nullptr, nullptr, buf1, NN);
  gemm_kernel<128, 128, 0><<<GG, 256, 0, stream>>>(buf2, Wr2, br2, nullptr, nullptr, nullptr, nullptr, buf0, NN);
  gat_edge_kernel<<<GW, 256, 0, stream>>>(buf1, buf0, att2, bias2, g2, be2, m2, v2,
                                          buf2 /*H*/, buf0 /*OUT in-place*/, rowptr, csr, NN);
  // out head
  gemm_kernel<128, 64, 2><<<GG, 256, 0, stream>>>(buf0, Wo1, bo1, nullptr, nullptr, nullptr, nullptr, buf1, NN);
  out2_kernel<<<GW, 256, 0, stream>>>(buf1, Wo2, bo2, out, NN);
}

// Round 2
// 475.494 us; speedup vs baseline: 1.3105x; 1.3105x over previous
//
#include <hip/hip_runtime.h>
#include <hip/hip_bf16.h>

#define NN 50000
#define EE 800000
#define SCAN_B 196   // ceil(NN/256)

__device__ __forceinline__ float lrelu(float x, float s){ return fmaxf(x, x * s); }

// 16-lane all-reduce sum via DPP (pure VALU, no LDS).
__device__ __forceinline__ float dpp_add16(float x){
  int v = __float_as_int(x), t;
  t = __builtin_amdgcn_update_dpp(0, v, 0xB1, 0xF, 0xF, true);   // quad_perm [1,0,3,2]  (xor 1)
  v = __float_as_int(__int_as_float(v) + __int_as_float(t));
  t = __builtin_amdgcn_update_dpp(0, v, 0x4E, 0xF, 0xF, true);   // quad_perm [2,3,0,1]  (xor 2)
  v = __float_as_int(__int_as_float(v) + __int_as_float(t));
  t = __builtin_amdgcn_update_dpp(0, v, 0x141, 0xF, 0xF, true);  // row_half_mirror      (xor 4 eq.)
  v = __float_as_int(__int_as_float(v) + __int_as_float(t));
  t = __builtin_amdgcn_update_dpp(0, v, 0x140, 0xF, 0xF, true);  // row_mirror           (xor 8 eq.)
  v = __float_as_int(__int_as_float(v) + __int_as_float(t));
  return __int_as_float(v);
}

// ---------------- CSR build ----------------

__global__ void detect_kernel(const int* __restrict__ ei, int* __restrict__ flag){
  __shared__ int any;
  if (threadIdx.x == 0) any = 0;
  __syncthreads();
  if (ei[2 * threadIdx.x + 1] != 0) atomicOr(&any, 1);
  __syncthreads();
  if (threadIdx.x == 0) *flag = (any == 0) ? 1 : 0;
}

__global__ void zero1_kernel(int* __restrict__ a, int n){
  int i = blockIdx.x * blockDim.x + threadIdx.x;
  if (i < n) a[i] = 0;
}

__global__ void count_kernel(const int* __restrict__ ei, const int* __restrict__ flag,
                             int* __restrict__ deg){
  int e = blockIdx.x * blockDim.x + threadIdx.x;
  if (e >= EE) return;
  int f = *flag;
  int d = f ? ei[2 * (EE + e)] : ei[EE + e];
  atomicAdd(&deg[d], 1);
}

__global__ void scan1_kernel(const int* __restrict__ deg, int* __restrict__ rowptr,
                             int* __restrict__ bsum){
  __shared__ int tmp[256];
  int tid = threadIdx.x;
  int idx = blockIdx.x * 256 + tid;
  int v = (idx < NN) ? deg[idx] : 0;
  tmp[tid] = v;
  __syncthreads();
  for (int off = 1; off < 256; off <<= 1){
    int t = (tid >= off) ? tmp[tid - off] : 0;
    __syncthreads();
    tmp[tid] += t;
    __syncthreads();
  }
  if (idx < NN) rowptr[idx] = tmp[tid] - v;          // block-local exclusive
  if (tid == 255) bsum[blockIdx.x] = tmp[255];
}

__global__ void scan2_kernel(const int* __restrict__ bsum, int* __restrict__ boff,
                             int* __restrict__ rowptr){
  __shared__ int tmp[256];
  int tid = threadIdx.x;
  int v = (tid < SCAN_B) ? bsum[tid] : 0;
  tmp[tid] = v;
  __syncthreads();
  for (int off = 1; off < 256; off <<= 1){
    int t = (tid >= off) ? tmp[tid - off] : 0;
    __syncthreads();
    tmp[tid] += t;
    __syncthreads();
  }
  if (tid < SCAN_B) boff[tid] = tmp[tid] - v;
  if (tid == 255) rowptr[NN] = tmp[255];
}

__global__ void scan3_kernel(int* __restrict__ rowptr, const int* __restrict__ boff,
                             int* __restrict__ deg){
  int i = blockIdx.x * 256 + threadIdx.x;
  if (i < NN){ rowptr[i] += boff[blockIdx.x]; deg[i] = 0; }   // deg reused as cursor
}

__global__ void scatter_kernel(const int* __restrict__ ei, const int* __restrict__ flag,
                               const int* __restrict__ rowptr, int* __restrict__ cursor,
                               int* __restrict__ csr_src){
  int e = blockIdx.x * blockDim.x + threadIdx.x;
  if (e >= EE) return;
  int f = *flag;
  int s = f ? ei[2 * e] : ei[e];
  int d = f ? ei[2 * (EE + e)] : ei[EE + e];
  int pos = atomicAdd(&cursor[d], 1);
  csr_src[rowptr[d] + pos] = s;
}

// ---------------- fused SGEMM (512 threads, 128 x KOUT tile) ----------------
// EPI: 0 = +bias ; 1 = +bias, BN, leaky(0.1) ; 2 = +bias, leaky(0.1)
template<int KIN, int KOUT, int EPI>
__launch_bounds__(512)
__global__ void gemm_kernel(const float* __restrict__ A, const float* __restrict__ W,
                            const float* __restrict__ bias,
                            const float* __restrict__ bn_g, const float* __restrict__ bn_b,
                            const float* __restrict__ bn_m, const float* __restrict__ bn_v,
                            float* __restrict__ out, int n){
  constexpr int CG  = KOUT / 8;     // col-groups (each thread owns 2 float4 col blocks)
  constexpr int RG  = 512 / CG;     // row-groups
  constexpr int RPT = 128 / RG;     // rows per thread
  constexpr int SAS = KIN + 4;      // padded A stride
  constexpr int SWS = KOUT;
  __shared__ float sA[128 * SAS];
  __shared__ float sW[KIN * SWS];
  const int tid = threadIdx.x;
  const long r0 = (long)blockIdx.x * 128;

  for (int idx = tid; idx < KIN * KOUT / 4; idx += 512){
    float4 w = reinterpret_cast<const float4*>(W)[idx];
    int k = idx / (KOUT / 4), c4 = idx % (KOUT / 4);
    *reinterpret_cast<float4*>(&sW[k * SWS + c4 * 4]) = w;
  }
  for (int idx = tid; idx < 128 * (KIN / 4); idx += 512){
    int r = idx / (KIN / 4), k4 = idx % (KIN / 4);
    float4 a = make_float4(0.f, 0.f, 0.f, 0.f);
    if (r0 + r < n) a = reinterpret_cast<const float4*>(A)[(r0 + r) * (KIN / 4) + k4];
    *reinterpret_cast<float4*>(&sA[r * SAS + k4 * 4]) = a;
  }
  __syncthreads();

  const int tr = tid / CG;            // 0..RG-1
  const int tc = tid % CG;
  const int c0 = tc * 4;
  const int c1 = KOUT / 2 + tc * 4;

  float acc[RPT][8];
  #pragma unroll
  for (int i = 0; i < RPT; i++)
    #pragma unroll
    for (int j = 0; j < 8; j++) acc[i][j] = 0.f;

  for (int k = 0; k < KIN; k += 4){
    float4 a4[RPT];
    #pragma unroll
    for (int i = 0; i < RPT; i++)
      a4[i] = *reinterpret_cast<const float4*>(&sA[(tr + RG * i) * SAS + k]);
    #pragma unroll
    for (int kk = 0; kk < 4; kk++){
      float4 w0 = *reinterpret_cast<const float4*>(&sW[(k + kk) * SWS + c0]);
      float4 w1 = *reinterpret_cast<const float4*>(&sW[(k + kk) * SWS + c1]);
      #pragma unroll
      for (int i = 0; i < RPT; i++){
        float av = (kk == 0) ? a4[i].x : (kk == 1) ? a4[i].y : (kk == 2) ? a4[i].z : a4[i].w;
        acc[i][0] = fmaf(av, w0.x, acc[i][0]);
        acc[i][1] = fmaf(av, w0.y, acc[i][1]);
        acc[i][2] = fmaf(av, w0.z, acc[i][2]);
        acc[i][3] = fmaf(av, w0.w, acc[i][3]);
        acc[i][4] = fmaf(av, w1.x, acc[i][4]);
        acc[i][5] = fmaf(av, w1.y, acc[i][5]);
        acc[i][6] = fmaf(av, w1.z, acc[i][6]);
        acc[i][7] = fmaf(av, w1.w, acc[i][7]);
      }
    }
  }

  float cb[8], cg_[8], cbb[8], cm[8], cv[8];
  #pragma unroll
  for (int j = 0; j < 8; j++){
    int c = (j < 4) ? (c0 + j) : (c1 + j - 4);
    cb[j] = bias[c];
    if (EPI == 1){ cg_[j] = bn_g[c]; cbb[j] = bn_b[c]; cm[j] = bn_m[c]; cv[j] = bn_v[c]; }
  }
  #pragma unroll
  for (int i = 0; i < RPT; i++){
    long r = r0 + tr + RG * i;
    if (r < n){
      float vv[8];
      #pragma unroll
      for (int j = 0; j < 8; j++){
        float v = acc[i][j] + cb[j];
        if (EPI == 1){
          v = (v - cm[j]) * rsqrtf(cv[j] + 1e-5f) * cg_[j] + cbb[j];
          v = lrelu(v, 0.1f);
        }
        if (EPI == 2){ v = lrelu(v, 0.1f); }
        vv[j] = v;
      }
      *reinterpret_cast<float4*>(&out[r * KOUT + c0]) = make_float4(vv[0], vv[1], vv[2], vv[3]);
      *reinterpret_cast<float4*>(&out[r * KOUT + c1]) = make_float4(vv[4], vv[5], vv[6], vv[7]);
    }
  }
}

// ---------------- GATv2 edge phase ----------------
// One wave per dst node. Lane l owns channels cb, cb+1 where
// cb = (l>>4)*32 + (l&15)*2  -> both channels in head (l>>4).
// Logit reduce = 4-step DPP over the 16-lane head group (no DS ops).
// Online softmax per lane (single head state). Epilogue fuses
// /den, +bias, BN, leaky(0.1), +H. OUT may alias XR.
__global__ void gat_edge_kernel(const float* __restrict__ XL, const float* __restrict__ XR,
                                const float* __restrict__ att, const float* __restrict__ bias,
                                const float* __restrict__ bn_g, const float* __restrict__ bn_b,
                                const float* __restrict__ bn_m, const float* __restrict__ bn_v,
                                const float* __restrict__ H, float* __restrict__ OUT,
                                const int* __restrict__ rowptr, const int* __restrict__ csr_src,
                                int n){
  int wid  = (int)((blockIdx.x * blockDim.x + threadIdx.x) >> 6);
  int lane = threadIdx.x & 63;
  if (wid >= n) return;
  const int d = wid;
  const int cb = ((lane >> 4) << 5) + ((lane & 15) << 1);
  const float2 a2 = *reinterpret_cast<const float2*>(att + cb);
  const float2 xr = *reinterpret_cast<const float2*>(XR + (long)d * 128 + cb);
  const float2 xd = *reinterpret_cast<const float2*>(XL + (long)d * 128 + cb);

  // self loop first
  float s0 = lrelu(xr.x + xd.x, 0.2f);
  float s1 = lrelu(xr.y + xd.y, 0.2f);
  float m = dpp_add16(fmaf(a2.x, s0, a2.y * s1));
  float den = 1.f;
  float2 O = xd;

  const int start = rowptr[d], end = rowptr[d + 1];
  float2 nxs = make_float2(0.f, 0.f);
  if (start < end){
    int si = csr_src[start];
    nxs = *reinterpret_cast<const float2*>(XL + (long)si * 128 + cb);
  }
  for (int e = start; e < end; e++){
    float2 xs = nxs;
    if (e + 1 < end){
      int si = csr_src[e + 1];
      nxs = *reinterpret_cast<const float2*>(XL + (long)si * 128 + cb);
    }
    s0 = lrelu(xr.x + xs.x, 0.2f);
    s1 = lrelu(xr.y + xs.y, 0.2f);
    float l = dpp_add16(fmaf(a2.x, s0, a2.y * s1));
    float nm = fmaxf(m, l);
    float sc = __expf(m - nm);
    float w  = __expf(l - nm);
    den = den * sc + w;
    O.x = O.x * sc + w * xs.x;
    O.y = O.y * sc + w * xs.y;
    m = nm;
  }

  float inv = 1.f / (den + 1e-16f);
  float v0 = O.x * inv + bias[cb];
  float v1 = O.y * inv + bias[cb + 1];
  v0 = (v0 - bn_m[cb])     * rsqrtf(bn_v[cb]     + 1e-5f) * bn_g[cb]     + bn_b[cb];
  v1 = (v1 - bn_m[cb + 1]) * rsqrtf(bn_v[cb + 1] + 1e-5f) * bn_g[cb + 1] + bn_b[cb + 1];
  const float2 h2 = *reinterpret_cast<const float2*>(H + (long)d * 128 + cb);
  float2 res;
  res.x = lrelu(v0, 0.1f) + h2.x;
  res.y = lrelu(v1, 0.1f) + h2.y;
  *reinterpret_cast<float2*>(OUT + (long)d * 128 + cb) = res;
}

// ---------------- final 64->1 projection ----------------
__global__ void out2_kernel(const float* __restrict__ Hin, const float* __restrict__ Wo2,
                            const float* __restrict__ bo2, float* __restrict__ out, int n){
  int wid  = (int)((blockIdx.x * blockDim.x + threadIdx.x) >> 6);
  int lane = threadIdx.x & 63;
  if (wid >= n) return;
  float p = Hin[(long)wid * 64 + lane] * Wo2[lane];
  #pragma unroll
  for (int off = 1; off < 64; off <<= 1) p += __shfl_xor(p, off);
  if (lane == 0) out[wid] = p + bo2[0];
}

// ---------------- launch ----------------
extern "C" void kernel_launch(void* const* d_in, const int* in_sizes, int n_in,
                              void* d_out, int out_size, void* d_ws, size_t ws_size,
                              hipStream_t stream) {
  const float* x     = (const float*)d_in[0];
  const int*   ei    = (const int*)  d_in[1];
  const float* W_pre = (const float*)d_in[2];
  const float* b_pre = (const float*)d_in[3];
  const float* g_pre = (const float*)d_in[4];
  const float* be_pre= (const float*)d_in[5];
  const float* m_pre = (const float*)d_in[6];
  const float* v_pre = (const float*)d_in[7];
  const float* Wl1  = (const float*)d_in[8];
  const float* bl1  = (const float*)d_in[9];
  const float* Wr1  = (const float*)d_in[10];
  const float* br1  = (const float*)d_in[11];
  const float* att1 = (const float*)d_in[12];
  const float* bias1= (const float*)d_in[13];
  const float* g1   = (const float*)d_in[14];
  const float* be1  = (const float*)d_in[15];
  const float* m1   = (const float*)d_in[16];
  const float* v1   = (const float*)d_in[17];
  const float* Wl2  = (const float*)d_in[18];
  const float* bl2  = (const float*)d_in[19];
  const float* Wr2  = (const float*)d_in[20];
  const float* br2  = (const float*)d_in[21];
  const float* att2 = (const float*)d_in[22];
  const float* bias2= (const float*)d_in[23];
  const float* g2   = (const float*)d_in[24];
  const float* be2  = (const float*)d_in[25];
  const float* m2   = (const float*)d_in[26];
  const float* v2   = (const float*)d_in[27];
  const float* Wo1  = (const float*)d_in[28];
  const float* bo1  = (const float*)d_in[29];
  const float* Wo2  = (const float*)d_in[30];
  const float* bo2  = (const float*)d_in[31];
  float* out = (float*)d_out;
  char*  ws  = (char*)d_ws;

  float* buf0 = (float*)(ws + 0);           // [N,128]
  float* buf1 = (float*)(ws + 25600000);    // [N,128]
  float* buf2 = (float*)(ws + 51200000);    // [N,128]
  int* rowptr = (int*)(ws + 76800000);      // N+1
  int* deg    = (int*)(ws + 77000448);      // N   (reused as scatter cursor)
  int* bsum   = (int*)(ws + 77200448);      // SCAN_B
  int* boff   = (int*)(ws + 77201472);      // SCAN_B
  int* csr    = (int*)(ws + 77400448);      // E
  int* flag   = (int*)(ws + 80600448);      // 1

  // CSR build (reused by both GAT layers)
  detect_kernel<<<1, 256, 0, stream>>>(ei, flag);
  zero1_kernel<<<SCAN_B, 256, 0, stream>>>(deg, NN);
  count_kernel<<<(EE + 255) / 256, 256, 0, stream>>>(ei, flag, deg);
  scan1_kernel<<<SCAN_B, 256, 0, stream>>>(deg, rowptr, bsum);
  scan2_kernel<<<1, 256, 0, stream>>>(bsum, boff, rowptr);
  scan3_kernel<<<SCAN_B, 256, 0, stream>>>(rowptr, boff, deg);   // also zeroes deg -> cursor
  scatter_kernel<<<(EE + 255) / 256, 256, 0, stream>>>(ei, flag, rowptr, deg, csr);

  const int GG = (NN + 127) / 128;   // 391 GEMM blocks
  const int GW = (NN + 3) / 4;       // wave-per-node blocks

  // pre: x0 = leaky(BN(x@W_pre + b_pre)) -> buf0
  gemm_kernel<64, 128, 1><<<GG, 512, 0, stream>>>(x, W_pre, b_pre, g_pre, be_pre, m_pre, v_pre, buf0, NN);
  // layer 1
  gemm_kernel<128, 128, 0><<<GG, 512, 0, stream>>>(buf0, Wl1, bl1, nullptr, nullptr, nullptr, nullptr, buf1, NN);
  gemm_kernel<128, 128, 0><<<GG, 512, 0, stream>>>(buf0, Wr1, br1, nullptr, nullptr, nullptr, nullptr, buf2, NN);
  gat_edge_kernel<<<GW, 256, 0, stream>>>(buf1, buf2, att1, bias1, g1, be1, m1, v1,
                                          buf0 /*H*/, buf2 /*OUT in-place*/, rowptr, csr, NN);
  // layer 2
  gemm_kernel<128, 128, 0><<<GG, 512, 0, stream>>>(buf2, Wl2, bl2, nullptr, nullptr, nullptr, nullptr, buf1, NN);
  gemm_kernel<128, 128, 0><<<GG, 512, 0, stream>>>(buf2, Wr2, br2, nullptr, nullptr, nullptr, nullptr, buf0, NN);
  gat_edge_kernel<<<GW, 256, 0, stream>>>(buf1, buf0, att2, bias2, g2, be2, m2, v2,
                                          buf2 /*H*/, buf0 /*OUT in-place*/, rowptr, csr, NN);
  // out head
  gemm_kernel<128, 64, 2><<<GG, 512, 0, stream>>>(buf0, Wo1, bo1, nullptr, nullptr, nullptr, nullptr, buf1, NN);
  out2_kernel<<<GW, 256, 0, stream>>>(buf1, Wo2, bo2, out, NN);
}

// Round 3
// 413.469 us; speedup vs baseline: 1.5071x; 1.1500x over previous
//
#include <hip/hip_runtime.h>
#include <hip/hip_bf16.h>

#define NN 50000
#define EE 800000
#define SCAN_B 196   // ceil(NN/256)

__device__ __forceinline__ float lrelu(float x, float s){ return fmaxf(x, x * s); }

// 16-lane all-reduce sum via DPP (pure VALU, no LDS).
__device__ __forceinline__ float dpp_add16(float x){
  int v = __float_as_int(x), t;
  t = __builtin_amdgcn_update_dpp(0, v, 0xB1, 0xF, 0xF, true);   // quad_perm [1,0,3,2]
  v = __float_as_int(__int_as_float(v) + __int_as_float(t));
  t = __builtin_amdgcn_update_dpp(0, v, 0x4E, 0xF, 0xF, true);   // quad_perm [2,3,0,1]
  v = __float_as_int(__int_as_float(v) + __int_as_float(t));
  t = __builtin_amdgcn_update_dpp(0, v, 0x141, 0xF, 0xF, true);  // row_half_mirror
  v = __float_as_int(__int_as_float(v) + __int_as_float(t));
  t = __builtin_amdgcn_update_dpp(0, v, 0x140, 0xF, 0xF, true);  // row_mirror
  v = __float_as_int(__int_as_float(v) + __int_as_float(t));
  return __int_as_float(v);
}

// ---------------- CSR build ----------------

__global__ void detect_kernel(const int* __restrict__ ei, int* __restrict__ flag){
  __shared__ int any;
  if (threadIdx.x == 0) any = 0;
  __syncthreads();
  if (ei[2 * threadIdx.x + 1] != 0) atomicOr(&any, 1);
  __syncthreads();
  if (threadIdx.x == 0) *flag = (any == 0) ? 1 : 0;
}

__global__ void zero1_kernel(int* __restrict__ a, int n){
  int i = blockIdx.x * blockDim.x + threadIdx.x;
  if (i < n) a[i] = 0;
}

__global__ void count_kernel(const int* __restrict__ ei, const int* __restrict__ flag,
                             int* __restrict__ deg){
  int e = blockIdx.x * blockDim.x + threadIdx.x;
  if (e >= EE) return;
  int d;
  if (*flag){
    const long long* eil = (const long long*)ei;
    d = (int)eil[EE + e];
  } else {
    d = ei[EE + e];
  }
  atomicAdd(&deg[d], 1);
}

__global__ void scan1_kernel(const int* __restrict__ deg, int* __restrict__ rowptr,
                             int* __restrict__ bsum){
  __shared__ int tmp[256];
  int tid = threadIdx.x;
  int idx = blockIdx.x * 256 + tid;
  int v = (idx < NN) ? deg[idx] : 0;
  tmp[tid] = v;
  __syncthreads();
  for (int off = 1; off < 256; off <<= 1){
    int t = (tid >= off) ? tmp[tid - off] : 0;
    __syncthreads();
    tmp[tid] += t;
    __syncthreads();
  }
  if (idx < NN) rowptr[idx] = tmp[tid] - v;          // block-local exclusive
  if (tid == 255) bsum[blockIdx.x] = tmp[255];
}

__global__ void scan2_kernel(const int* __restrict__ bsum, int* __restrict__ boff,
                             int* __restrict__ rowptr){
  __shared__ int tmp[256];
  int tid = threadIdx.x;
  int v = (tid < SCAN_B) ? bsum[tid] : 0;
  tmp[tid] = v;
  __syncthreads();
  for (int off = 1; off < 256; off <<= 1){
    int t = (tid >= off) ? tmp[tid - off] : 0;
    __syncthreads();
    tmp[tid] += t;
    __syncthreads();
  }
  if (tid < SCAN_B) boff[tid] = tmp[tid] - v;
  if (tid == 255) rowptr[NN] = tmp[255];
}

__global__ void scan3_kernel(int* __restrict__ rowptr, const int* __restrict__ boff,
                             int* __restrict__ deg){
  int i = blockIdx.x * 256 + threadIdx.x;
  if (i < NN){ rowptr[i] += boff[blockIdx.x]; deg[i] = 0; }   // deg reused as cursor
}

__global__ void scatter_kernel(const int* __restrict__ ei, const int* __restrict__ flag,
                               const int* __restrict__ rowptr, int* __restrict__ cursor,
                               int* __restrict__ csr_src){
  int e = blockIdx.x * blockDim.x + threadIdx.x;
  if (e >= EE) return;
  int s, d;
  if (*flag){
    const long long* eil = (const long long*)ei;
    s = (int)eil[e];
    d = (int)eil[EE + e];
  } else {
    s = ei[e];
    d = ei[EE + e];
  }
  int pos = atomicAdd(&cursor[d], 1);
  csr_src[rowptr[d] + pos] = s;
}

// ---------------- fused SGEMM (512 threads, 128 x KOUT tile) ----------------
// EPI: 0 = +bias ; 1 = +bias, BN, leaky(0.1) ; 2 = +bias, leaky(0.1)
template<int KIN, int KOUT, int EPI>
__launch_bounds__(512)
__global__ void gemm_kernel(const float* __restrict__ A, const float* __restrict__ W,
                            const float* __restrict__ bias,
                            const float* __restrict__ bn_g, const float* __restrict__ bn_b,
                            const float* __restrict__ bn_m, const float* __restrict__ bn_v,
                            float* __restrict__ out, int n){
  constexpr int CG  = KOUT / 8;
  constexpr int RG  = 512 / CG;
  constexpr int RPT = 128 / RG;
  constexpr int SAS = KIN + 4;
  constexpr int SWS = KOUT;
  __shared__ float sA[128 * SAS];
  __shared__ float sW[KIN * SWS];
  const int tid = threadIdx.x;
  const long r0 = (long)blockIdx.x * 128;

  for (int idx = tid; idx < KIN * KOUT / 4; idx += 512){
    float4 w = reinterpret_cast<const float4*>(W)[idx];
    int k = idx / (KOUT / 4), c4 = idx % (KOUT / 4);
    *reinterpret_cast<float4*>(&sW[k * SWS + c4 * 4]) = w;
  }
  for (int idx = tid; idx < 128 * (KIN / 4); idx += 512){
    int r = idx / (KIN / 4), k4 = idx % (KIN / 4);
    float4 a = make_float4(0.f, 0.f, 0.f, 0.f);
    if (r0 + r < n) a = reinterpret_cast<const float4*>(A)[(r0 + r) * (KIN / 4) + k4];
    *reinterpret_cast<float4*>(&sA[r * SAS + k4 * 4]) = a;
  }
  __syncthreads();

  const int tr = tid / CG;
  const int tc = tid % CG;
  const int c0 = tc * 4;
  const int c1 = KOUT / 2 + tc * 4;

  float acc[RPT][8];
  #pragma unroll
  for (int i = 0; i < RPT; i++)
    #pragma unroll
    for (int j = 0; j < 8; j++) acc[i][j] = 0.f;

  for (int k = 0; k < KIN; k += 4){
    float4 a4[RPT];
    #pragma unroll
    for (int i = 0; i < RPT; i++)
      a4[i] = *reinterpret_cast<const float4*>(&sA[(tr + RG * i) * SAS + k]);
    #pragma unroll
    for (int kk = 0; kk < 4; kk++){
      float4 w0 = *reinterpret_cast<const float4*>(&sW[(k + kk) * SWS + c0]);
      float4 w1 = *reinterpret_cast<const float4*>(&sW[(k + kk) * SWS + c1]);
      #pragma unroll
      for (int i = 0; i < RPT; i++){
        float av = (kk == 0) ? a4[i].x : (kk == 1) ? a4[i].y : (kk == 2) ? a4[i].z : a4[i].w;
        acc[i][0] = fmaf(av, w0.x, acc[i][0]);
        acc[i][1] = fmaf(av, w0.y, acc[i][1]);
        acc[i][2] = fmaf(av, w0.z, acc[i][2]);
        acc[i][3] = fmaf(av, w0.w, acc[i][3]);
        acc[i][4] = fmaf(av, w1.x, acc[i][4]);
        acc[i][5] = fmaf(av, w1.y, acc[i][5]);
        acc[i][6] = fmaf(av, w1.z, acc[i][6]);
        acc[i][7] = fmaf(av, w1.w, acc[i][7]);
      }
    }
  }

  float cb[8], cg_[8], cbb[8], cm[8], cv[8];
  #pragma unroll
  for (int j = 0; j < 8; j++){
    int c = (j < 4) ? (c0 + j) : (c1 + j - 4);
    cb[j] = bias[c];
    if (EPI == 1){ cg_[j] = bn_g[c]; cbb[j] = bn_b[c]; cm[j] = bn_m[c]; cv[j] = bn_v[c]; }
  }
  #pragma unroll
  for (int i = 0; i < RPT; i++){
    long r = r0 + tr + RG * i;
    if (r < n){
      float vv[8];
      #pragma unroll
      for (int j = 0; j < 8; j++){
        float v = acc[i][j] + cb[j];
        if (EPI == 1){
          v = (v - cm[j]) * rsqrtf(cv[j] + 1e-5f) * cg_[j] + cbb[j];
          v = lrelu(v, 0.1f);
        }
        if (EPI == 2){ v = lrelu(v, 0.1f); }
        vv[j] = v;
      }
      *reinterpret_cast<float4*>(&out[r * KOUT + c0]) = make_float4(vv[0], vv[1], vv[2], vv[3]);
      *reinterpret_cast<float4*>(&out[r * KOUT + c1]) = make_float4(vv[4], vv[5], vv[6], vv[7]);
    }
  }
}

// ---------------- GATv2 edge phase ----------------
// One wave per dst node. Lane l owns channels cb, cb+1 of head (l>>4).
// Batch-4 edges per iteration: 4 gathers in flight (+4 prefetch), 4 pipelined
// DPP trees, ONE online-softmax rescale per batch. Epilogue fuses
// /den, +bias, BN, leaky(0.1), +H. OUT may alias XR (own-row only).
__global__ void gat_edge_kernel(const float* __restrict__ XL, const float* __restrict__ XR,
                                const float* __restrict__ att, const float* __restrict__ bias,
                                const float* __restrict__ bn_g, const float* __restrict__ bn_b,
                                const float* __restrict__ bn_m, const float* __restrict__ bn_v,
                                const float* __restrict__ H, float* __restrict__ OUT,
                                const int* __restrict__ rowptr, const int* __restrict__ csr_src,
                                int n){
  int wid  = (int)((blockIdx.x * blockDim.x + threadIdx.x) >> 6);
  int lane = threadIdx.x & 63;
  if (wid >= n) return;
  const int d = wid;
  const int cb = ((lane >> 4) << 5) + ((lane & 15) << 1);
  const float2 a2 = *reinterpret_cast<const float2*>(att + cb);
  const float2 xr = *reinterpret_cast<const float2*>(XR + (long)d * 128 + cb);
  const float2 xd = *reinterpret_cast<const float2*>(XL + (long)d * 128 + cb);

  // self loop = initial state
  float m = dpp_add16(fmaf(a2.x, lrelu(xr.x + xd.x, 0.2f), a2.y * lrelu(xr.y + xd.y, 0.2f)));
  float den = 1.f;
  float2 O = xd;

  const int start = rowptr[d], end = rowptr[d + 1];
  const int nfull = (end - start) >> 2;
  int e = start;

  float2 c0, c1, c2, c3;
  if (nfull > 0){
    int i0 = csr_src[e], i1 = csr_src[e + 1], i2 = csr_src[e + 2], i3 = csr_src[e + 3];
    c0 = *reinterpret_cast<const float2*>(XL + (long)i0 * 128 + cb);
    c1 = *reinterpret_cast<const float2*>(XL + (long)i1 * 128 + cb);
    c2 = *reinterpret_cast<const float2*>(XL + (long)i2 * 128 + cb);
    c3 = *reinterpret_cast<const float2*>(XL + (long)i3 * 128 + cb);
  }
  for (int b = 0; b < nfull; b++){
    float2 u0 = c0, u1 = c1, u2 = c2, u3 = c3;
    if (b + 1 < nfull){
      int j0 = csr_src[e + 4], j1 = csr_src[e + 5], j2 = csr_src[e + 6], j3 = csr_src[e + 7];
      c0 = *reinterpret_cast<const float2*>(XL + (long)j0 * 128 + cb);
      c1 = *reinterpret_cast<const float2*>(XL + (long)j1 * 128 + cb);
      c2 = *reinterpret_cast<const float2*>(XL + (long)j2 * 128 + cb);
      c3 = *reinterpret_cast<const float2*>(XL + (long)j3 * 128 + cb);
    }
    float t0 = fmaf(a2.x, lrelu(xr.x + u0.x, 0.2f), a2.y * lrelu(xr.y + u0.y, 0.2f));
    float t1 = fmaf(a2.x, lrelu(xr.x + u1.x, 0.2f), a2.y * lrelu(xr.y + u1.y, 0.2f));
    float t2 = fmaf(a2.x, lrelu(xr.x + u2.x, 0.2f), a2.y * lrelu(xr.y + u2.y, 0.2f));
    float t3 = fmaf(a2.x, lrelu(xr.x + u3.x, 0.2f), a2.y * lrelu(xr.y + u3.y, 0.2f));
    float l0 = dpp_add16(t0);
    float l1 = dpp_add16(t1);
    float l2 = dpp_add16(t2);
    float l3 = dpp_add16(t3);
    float bm = fmaxf(fmaxf(l0, l1), fmaxf(l2, l3));
    float nm = fmaxf(m, bm);
    float sc = __expf(m - nm);
    float w0 = __expf(l0 - nm);
    float w1 = __expf(l1 - nm);
    float w2 = __expf(l2 - nm);
    float w3 = __expf(l3 - nm);
    den = fmaf(den, sc, (w0 + w1) + (w2 + w3));
    O.x = fmaf(O.x, sc, fmaf(w0, u0.x, fmaf(w1, u1.x, fmaf(w2, u2.x, w3 * u3.x))));
    O.y = fmaf(O.y, sc, fmaf(w0, u0.y, fmaf(w1, u1.y, fmaf(w2, u2.y, w3 * u3.y))));
    m = nm;
    e += 4;
  }
  // tail (0..3 edges)
  for (; e < end; e++){
    int si = csr_src[e];
    float2 xs = *reinterpret_cast<const float2*>(XL + (long)si * 128 + cb);
    float l = dpp_add16(fmaf(a2.x, lrelu(xr.x + xs.x, 0.2f), a2.y * lrelu(xr.y + xs.y, 0.2f)));
    float nm = fmaxf(m, l);
    float sc = __expf(m - nm);
    float w  = __expf(l - nm);
    den = fmaf(den, sc, w);
    O.x = fmaf(O.x, sc, w * xs.x);
    O.y = fmaf(O.y, sc, w * xs.y);
    m = nm;
  }

  float inv = 1.f / (den + 1e-16f);
  float v0 = O.x * inv + bias[cb];
  float v1 = O.y * inv + bias[cb + 1];
  v0 = (v0 - bn_m[cb])     * rsqrtf(bn_v[cb]     + 1e-5f) * bn_g[cb]     + bn_b[cb];
  v1 = (v1 - bn_m[cb + 1]) * rsqrtf(bn_v[cb + 1] + 1e-5f) * bn_g[cb + 1] + bn_b[cb + 1];
  const float2 h2 = *reinterpret_cast<const float2*>(H + (long)d * 128 + cb);
  float2 res;
  res.x = lrelu(v0, 0.1f) + h2.x;
  res.y = lrelu(v1, 0.1f) + h2.y;
  *reinterpret_cast<float2*>(OUT + (long)d * 128 + cb) = res;
}

// ---------------- final 64->1 projection ----------------
__global__ void out2_kernel(const float* __restrict__ Hin, const float* __restrict__ Wo2,
                            const float* __restrict__ bo2, float* __restrict__ out, int n){
  int wid  = (int)((blockIdx.x * blockDim.x + threadIdx.x) >> 6);
  int lane = threadIdx.x & 63;
  if (wid >= n) return;
  float p = Hin[(long)wid * 64 + lane] * Wo2[lane];
  #pragma unroll
  for (int off = 1; off < 64; off <<= 1) p += __shfl_xor(p, off);
  if (lane == 0) out[wid] = p + bo2[0];
}

// ---------------- launch ----------------
extern "C" void kernel_launch(void* const* d_in, const int* in_sizes, int n_in,
                              void* d_out, int out_size, void* d_ws, size_t ws_size,
                              hipStream_t stream) {
  const float* x     = (const float*)d_in[0];
  const int*   ei    = (const int*)  d_in[1];
  const float* W_pre = (const float*)d_in[2];
  const float* b_pre = (const float*)d_in[3];
  const float* g_pre = (const float*)d_in[4];
  const float* be_pre= (const float*)d_in[5];
  const float* m_pre = (const float*)d_in[6];
  const float* v_pre = (const float*)d_in[7];
  const float* Wl1  = (const float*)d_in[8];
  const float* bl1  = (const float*)d_in[9];
  const float* Wr1  = (const float*)d_in[10];
  const float* br1  = (const float*)d_in[11];
  const float* att1 = (const float*)d_in[12];
  const float* bias1= (const float*)d_in[13];
  const float* g1   = (const float*)d_in[14];
  const float* be1  = (const float*)d_in[15];
  const float* m1   = (const float*)d_in[16];
  const float* v1   = (const float*)d_in[17];
  const float* Wl2  = (const float*)d_in[18];
  const float* bl2  = (const float*)d_in[19];
  const float* Wr2  = (const float*)d_in[20];
  const float* br2  = (const float*)d_in[21];
  const float* att2 = (const float*)d_in[22];
  const float* bias2= (const float*)d_in[23];
  const float* g2   = (const float*)d_in[24];
  const float* be2  = (const float*)d_in[25];
  const float* m2   = (const float*)d_in[26];
  const float* v2   = (const float*)d_in[27];
  const float* Wo1  = (const float*)d_in[28];
  const float* bo1  = (const float*)d_in[29];
  const float* Wo2  = (const float*)d_in[30];
  const float* bo2  = (const float*)d_in[31];
  float* out = (float*)d_out;
  char*  ws  = (char*)d_ws;

  float* buf0 = (float*)(ws + 0);           // [N,128]
  float* buf1 = (float*)(ws + 25600000);    // [N,128]
  float* buf2 = (float*)(ws + 51200000);    // [N,128]
  int* rowptr = (int*)(ws + 76800000);      // N+1
  int* deg    = (int*)(ws + 77000448);      // N   (reused as scatter cursor)
  int* bsum   = (int*)(ws + 77200448);      // SCAN_B
  int* boff   = (int*)(ws + 77201472);      // SCAN_B
  int* csr    = (int*)(ws + 77400448);      // E
  int* flag   = (int*)(ws + 80600448);      // 1

  // CSR build (reused by both GAT layers)
  detect_kernel<<<1, 256, 0, stream>>>(ei, flag);
  zero1_kernel<<<SCAN_B, 256, 0, stream>>>(deg, NN);
  count_kernel<<<(EE + 255) / 256, 256, 0, stream>>>(ei, flag, deg);
  scan1_kernel<<<SCAN_B, 256, 0, stream>>>(deg, rowptr, bsum);
  scan2_kernel<<<1, 256, 0, stream>>>(bsum, boff, rowptr);
  scan3_kernel<<<SCAN_B, 256, 0, stream>>>(rowptr, boff, deg);   // also zeroes deg -> cursor
  scatter_kernel<<<(EE + 255) / 256, 256, 0, stream>>>(ei, flag, rowptr, deg, csr);

  const int GG = (NN + 127) / 128;
  const int GW = (NN + 3) / 4;

  // pre: x0 = leaky(BN(x@W_pre + b_pre)) -> buf0
  gemm_kernel<64, 128, 1><<<GG, 512, 0, stream>>>(x, W_pre, b_pre, g_pre, be_pre, m_pre, v_pre, buf0, NN);
  // layer 1
  gemm_kernel<128, 128, 0><<<GG, 512, 0, stream>>>(buf0, Wl1, bl1, nullptr, nullptr, nullptr, nullptr, buf1, NN);
  gemm_kernel<128, 128, 0><<<GG, 512, 0, stream>>>(buf0, Wr1, br1, nullptr, nullptr, nullptr, nullptr, buf2, NN);
  gat_edge_kernel<<<GW, 256, 0, stream>>>(buf1, buf2, att1, bias1, g1, be1, m1, v1,
                                          buf0 /*H*/, buf2 /*OUT in-place*/, rowptr, csr, NN);
  // layer 2
  gemm_kernel<128, 128, 0><<<GG, 512, 0, stream>>>(buf2, Wl2, bl2, nullptr, nullptr, nullptr, nullptr, buf1, NN);
  gemm_kernel<128, 128, 0><<<GG, 512, 0, stream>>>(buf2, Wr2, br2, nullptr, nullptr, nullptr, nullptr, buf0, NN);
  gat_edge_kernel<<<GW, 256, 0, stream>>>(buf1, buf0, att2, bias2, g2, be2, m2, v2,
                                          buf2 /*H*/, buf0 /*OUT in-place*/, rowptr, csr, NN);
  // out head
  gemm_kernel<128, 64, 2><<<GG, 512, 0, stream>>>(buf0, Wo1, bo1, nullptr, nullptr, nullptr, nullptr, buf1, NN);
  out2_kernel<<<GW, 256, 0, stream>>>(buf1, Wo2, bo2, out, NN);
}

// Round 4
// 381.844 us; speedup vs baseline: 1.6320x; 1.0828x over previous
//
#include <hip/hip_runtime.h>
#include <hip/hip_bf16.h>

#define NN 50000
#define EE 800000
#define SCAN_B 196   // ceil(NN/256)

typedef unsigned int uint;

__device__ __forceinline__ float lrelu(float x, float s){ return fmaxf(x, x * s); }

// RNE pack of two f32 -> 2x bf16 in one uint (lo = a, hi = b)
__device__ __forceinline__ uint pack_bf16(float a, float b){
  uint ua = __float_as_uint(a), ub = __float_as_uint(b);
  ua = (ua + 0x7FFFu + ((ua >> 16) & 1u)) >> 16;
  ub = (ub + 0x7FFFu + ((ub >> 16) & 1u)) >> 16;
  return ua | (ub << 16);
}

// 16-lane all-reduce sum via DPP (pure VALU, no LDS).
__device__ __forceinline__ float dpp_add16(float x){
  int v = __float_as_int(x), t;
  t = __builtin_amdgcn_update_dpp(0, v, 0xB1, 0xF, 0xF, true);   // quad_perm [1,0,3,2]
  v = __float_as_int(__int_as_float(v) + __int_as_float(t));
  t = __builtin_amdgcn_update_dpp(0, v, 0x4E, 0xF, 0xF, true);   // quad_perm [2,3,0,1]
  v = __float_as_int(__int_as_float(v) + __int_as_float(t));
  t = __builtin_amdgcn_update_dpp(0, v, 0x141, 0xF, 0xF, true);  // row_half_mirror
  v = __float_as_int(__int_as_float(v) + __int_as_float(t));
  t = __builtin_amdgcn_update_dpp(0, v, 0x140, 0xF, 0xF, true);  // row_mirror
  v = __float_as_int(__int_as_float(v) + __int_as_float(t));
  return __int_as_float(v);
}

// ---------------- CSR build ----------------

__global__ void detect_kernel(const int* __restrict__ ei, int* __restrict__ flag){
  __shared__ int any;
  if (threadIdx.x == 0) any = 0;
  __syncthreads();
  if (ei[2 * threadIdx.x + 1] != 0) atomicOr(&any, 1);
  __syncthreads();
  if (threadIdx.x == 0) *flag = (any == 0) ? 1 : 0;
}

__global__ void zero1_kernel(int* __restrict__ a, int n){
  int i = blockIdx.x * blockDim.x + threadIdx.x;
  if (i < n) a[i] = 0;
}

__global__ void count_kernel(const int* __restrict__ ei, const int* __restrict__ flag,
                             int* __restrict__ deg){
  int e = blockIdx.x * blockDim.x + threadIdx.x;
  if (e >= EE) return;
  int d;
  if (*flag){
    const long long* eil = (const long long*)ei;
    d = (int)eil[EE + e];
  } else {
    d = ei[EE + e];
  }
  atomicAdd(&deg[d], 1);
}

__global__ void scan1_kernel(const int* __restrict__ deg, int* __restrict__ rowptr,
                             int* __restrict__ bsum){
  __shared__ int tmp[256];
  int tid = threadIdx.x;
  int idx = blockIdx.x * 256 + tid;
  int v = (idx < NN) ? deg[idx] : 0;
  tmp[tid] = v;
  __syncthreads();
  for (int off = 1; off < 256; off <<= 1){
    int t = (tid >= off) ? tmp[tid - off] : 0;
    __syncthreads();
    tmp[tid] += t;
    __syncthreads();
  }
  if (idx < NN) rowptr[idx] = tmp[tid] - v;
  if (tid == 255) bsum[blockIdx.x] = tmp[255];
}

__global__ void scan2_kernel(const int* __restrict__ bsum, int* __restrict__ boff,
                             int* __restrict__ rowptr){
  __shared__ int tmp[256];
  int tid = threadIdx.x;
  int v = (tid < SCAN_B) ? bsum[tid] : 0;
  tmp[tid] = v;
  __syncthreads();
  for (int off = 1; off < 256; off <<= 1){
    int t = (tid >= off) ? tmp[tid - off] : 0;
    __syncthreads();
    tmp[tid] += t;
    __syncthreads();
  }
  if (tid < SCAN_B) boff[tid] = tmp[tid] - v;
  if (tid == 255) rowptr[NN] = tmp[255];
}

__global__ void scan3_kernel(int* __restrict__ rowptr, const int* __restrict__ boff,
                             int* __restrict__ deg){
  int i = blockIdx.x * 256 + threadIdx.x;
  if (i < NN){ rowptr[i] += boff[blockIdx.x]; deg[i] = 0; }   // deg reused as cursor
}

__global__ void scatter_kernel(const int* __restrict__ ei, const int* __restrict__ flag,
                               const int* __restrict__ rowptr, int* __restrict__ cursor,
                               int* __restrict__ csr_src){
  int e = blockIdx.x * blockDim.x + threadIdx.x;
  if (e >= EE) return;
  int s, d;
  if (*flag){
    const long long* eil = (const long long*)ei;
    s = (int)eil[e];
    d = (int)eil[EE + e];
  } else {
    s = ei[e];
    d = ei[EE + e];
  }
  int pos = atomicAdd(&cursor[d], 1);
  csr_src[rowptr[d] + pos] = s;
}

// ---------------- fused SGEMM (512 threads, 128 x KOUT tile) ----------------
// EPI: 0 = +bias ; 1 = +bias, BN, leaky(0.1) ; 2 = +bias, leaky(0.1)
template<int KIN, int KOUT, int EPI>
__launch_bounds__(512)
__global__ void gemm_kernel(const float* __restrict__ A, const float* __restrict__ W,
                            const float* __restrict__ bias,
                            const float* __restrict__ bn_g, const float* __restrict__ bn_b,
                            const float* __restrict__ bn_m, const float* __restrict__ bn_v,
                            float* __restrict__ out, int n){
  constexpr int CG  = KOUT / 8;
  constexpr int RG  = 512 / CG;
  constexpr int RPT = 128 / RG;
  constexpr int SAS = KIN + 4;
  constexpr int SWS = KOUT;
  __shared__ float sA[128 * SAS];
  __shared__ float sW[KIN * SWS];
  const int tid = threadIdx.x;
  const long r0 = (long)blockIdx.x * 128;

  for (int idx = tid; idx < KIN * KOUT / 4; idx += 512){
    float4 w = reinterpret_cast<const float4*>(W)[idx];
    int k = idx / (KOUT / 4), c4 = idx % (KOUT / 4);
    *reinterpret_cast<float4*>(&sW[k * SWS + c4 * 4]) = w;
  }
  for (int idx = tid; idx < 128 * (KIN / 4); idx += 512){
    int r = idx / (KIN / 4), k4 = idx % (KIN / 4);
    float4 a = make_float4(0.f, 0.f, 0.f, 0.f);
    if (r0 + r < n) a = reinterpret_cast<const float4*>(A)[(r0 + r) * (KIN / 4) + k4];
    *reinterpret_cast<float4*>(&sA[r * SAS + k4 * 4]) = a;
  }
  __syncthreads();

  const int tr = tid / CG;
  const int tc = tid % CG;
  const int c0 = tc * 4;
  const int c1 = KOUT / 2 + tc * 4;

  float acc[RPT][8];
  #pragma unroll
  for (int i = 0; i < RPT; i++)
    #pragma unroll
    for (int j = 0; j < 8; j++) acc[i][j] = 0.f;

  for (int k = 0; k < KIN; k += 4){
    float4 a4[RPT];
    #pragma unroll
    for (int i = 0; i < RPT; i++)
      a4[i] = *reinterpret_cast<const float4*>(&sA[(tr + RG * i) * SAS + k]);
    #pragma unroll
    for (int kk = 0; kk < 4; kk++){
      float4 w0 = *reinterpret_cast<const float4*>(&sW[(k + kk) * SWS + c0]);
      float4 w1 = *reinterpret_cast<const float4*>(&sW[(k + kk) * SWS + c1]);
      #pragma unroll
      for (int i = 0; i < RPT; i++){
        float av = (kk == 0) ? a4[i].x : (kk == 1) ? a4[i].y : (kk == 2) ? a4[i].z : a4[i].w;
        acc[i][0] = fmaf(av, w0.x, acc[i][0]);
        acc[i][1] = fmaf(av, w0.y, acc[i][1]);
        acc[i][2] = fmaf(av, w0.z, acc[i][2]);
        acc[i][3] = fmaf(av, w0.w, acc[i][3]);
        acc[i][4] = fmaf(av, w1.x, acc[i][4]);
        acc[i][5] = fmaf(av, w1.y, acc[i][5]);
        acc[i][6] = fmaf(av, w1.z, acc[i][6]);
        acc[i][7] = fmaf(av, w1.w, acc[i][7]);
      }
    }
  }

  float cb[8], cg_[8], cbb[8], cm[8], cv[8];
  #pragma unroll
  for (int j = 0; j < 8; j++){
    int c = (j < 4) ? (c0 + j) : (c1 + j - 4);
    cb[j] = bias[c];
    if (EPI == 1){ cg_[j] = bn_g[c]; cbb[j] = bn_b[c]; cm[j] = bn_m[c]; cv[j] = bn_v[c]; }
  }
  #pragma unroll
  for (int i = 0; i < RPT; i++){
    long r = r0 + tr + RG * i;
    if (r < n){
      float vv[8];
      #pragma unroll
      for (int j = 0; j < 8; j++){
        float v = acc[i][j] + cb[j];
        if (EPI == 1){
          v = (v - cm[j]) * rsqrtf(cv[j] + 1e-5f) * cg_[j] + cbb[j];
          v = lrelu(v, 0.1f);
        }
        if (EPI == 2){ v = lrelu(v, 0.1f); }
        vv[j] = v;
      }
      *reinterpret_cast<float4*>(&out[r * KOUT + c0]) = make_float4(vv[0], vv[1], vv[2], vv[3]);
      *reinterpret_cast<float4*>(&out[r * KOUT + c1]) = make_float4(vv[4], vv[5], vv[6], vv[7]);
    }
  }
}

// ---------------- dual SGEMM: XLh(bf16) = A@Wl+bl ; XR(f32) = A@Wr+br ----------------
// A-tile staged ONCE in LDS; two sequential W phases. KIN = KOUT = 128.
__launch_bounds__(512)
__global__ void dual_gemm_kernel(const float* __restrict__ A,
                                 const float* __restrict__ Wl, const float* __restrict__ bl,
                                 const float* __restrict__ Wr, const float* __restrict__ br,
                                 uint* __restrict__ XLh, float* __restrict__ XR, int n){
  constexpr int SAS = 132;
  __shared__ float sA[128 * SAS];
  __shared__ float sW[128 * 128];
  const int tid = threadIdx.x;
  const long r0 = (long)blockIdx.x * 128;

  for (int idx = tid; idx < 128 * 32; idx += 512){
    int r = idx / 32, k4 = idx % 32;
    float4 a = make_float4(0.f, 0.f, 0.f, 0.f);
    if (r0 + r < n) a = reinterpret_cast<const float4*>(A)[(r0 + r) * 32 + k4];
    *reinterpret_cast<float4*>(&sA[r * SAS + k4 * 4]) = a;
  }
  for (int idx = tid; idx < 4096; idx += 512)
    reinterpret_cast<float4*>(sW)[idx] = reinterpret_cast<const float4*>(Wl)[idx];
  __syncthreads();

  const int tr = tid / 16;          // 0..31
  const int tc = tid % 16;          // 0..15
  const int c0 = tc * 4;
  const int c1 = 64 + tc * 4;

  float acc[4][8];
  // ---- phase L ----
  #pragma unroll
  for (int i = 0; i < 4; i++)
    #pragma unroll
    for (int j = 0; j < 8; j++) acc[i][j] = 0.f;
  for (int k = 0; k < 128; k += 4){
    float4 a4[4];
    #pragma unroll
    for (int i = 0; i < 4; i++)
      a4[i] = *reinterpret_cast<const float4*>(&sA[(tr + 32 * i) * SAS + k]);
    #pragma unroll
    for (int kk = 0; kk < 4; kk++){
      float4 w0 = *reinterpret_cast<const float4*>(&sW[(k + kk) * 128 + c0]);
      float4 w1 = *reinterpret_cast<const float4*>(&sW[(k + kk) * 128 + c1]);
      #pragma unroll
      for (int i = 0; i < 4; i++){
        float av = (kk == 0) ? a4[i].x : (kk == 1) ? a4[i].y : (kk == 2) ? a4[i].z : a4[i].w;
        acc[i][0] = fmaf(av, w0.x, acc[i][0]);
        acc[i][1] = fmaf(av, w0.y, acc[i][1]);
        acc[i][2] = fmaf(av, w0.z, acc[i][2]);
        acc[i][3] = fmaf(av, w0.w, acc[i][3]);
        acc[i][4] = fmaf(av, w1.x, acc[i][4]);
        acc[i][5] = fmaf(av, w1.y, acc[i][5]);
        acc[i][6] = fmaf(av, w1.z, acc[i][6]);
        acc[i][7] = fmaf(av, w1.w, acc[i][7]);
      }
    }
  }
  {
    float b0[4], b1[4];
    #pragma unroll
    for (int j = 0; j < 4; j++){ b0[j] = bl[c0 + j]; b1[j] = bl[c1 + j]; }
    #pragma unroll
    for (int i = 0; i < 4; i++){
      long r = r0 + tr + 32 * i;
      if (r < n){
        uint2 pa, pb;
        pa.x = pack_bf16(acc[i][0] + b0[0], acc[i][1] + b0[1]);
        pa.y = pack_bf16(acc[i][2] + b0[2], acc[i][3] + b0[3]);
        pb.x = pack_bf16(acc[i][4] + b1[0], acc[i][5] + b1[1]);
        pb.y = pack_bf16(acc[i][6] + b1[2], acc[i][7] + b1[3]);
        *reinterpret_cast<uint2*>(&XLh[r * 64 + tc * 2])      = pa;
        *reinterpret_cast<uint2*>(&XLh[r * 64 + 32 + tc * 2]) = pb;
      }
    }
  }
  __syncthreads();
  // ---- phase R ----
  for (int idx = tid; idx < 4096; idx += 512)
    reinterpret_cast<float4*>(sW)[idx] = reinterpret_cast<const float4*>(Wr)[idx];
  __syncthreads();
  #pragma unroll
  for (int i = 0; i < 4; i++)
    #pragma unroll
    for (int j = 0; j < 8; j++) acc[i][j] = 0.f;
  for (int k = 0; k < 128; k += 4){
    float4 a4[4];
    #pragma unroll
    for (int i = 0; i < 4; i++)
      a4[i] = *reinterpret_cast<const float4*>(&sA[(tr + 32 * i) * SAS + k]);
    #pragma unroll
    for (int kk = 0; kk < 4; kk++){
      float4 w0 = *reinterpret_cast<const float4*>(&sW[(k + kk) * 128 + c0]);
      float4 w1 = *reinterpret_cast<const float4*>(&sW[(k + kk) * 128 + c1]);
      #pragma unroll
      for (int i = 0; i < 4; i++){
        float av = (kk == 0) ? a4[i].x : (kk == 1) ? a4[i].y : (kk == 2) ? a4[i].z : a4[i].w;
        acc[i][0] = fmaf(av, w0.x, acc[i][0]);
        acc[i][1] = fmaf(av, w0.y, acc[i][1]);
        acc[i][2] = fmaf(av, w0.z, acc[i][2]);
        acc[i][3] = fmaf(av, w0.w, acc[i][3]);
        acc[i][4] = fmaf(av, w1.x, acc[i][4]);
        acc[i][5] = fmaf(av, w1.y, acc[i][5]);
        acc[i][6] = fmaf(av, w1.z, acc[i][6]);
        acc[i][7] = fmaf(av, w1.w, acc[i][7]);
      }
    }
  }
  {
    float b0[4], b1[4];
    #pragma unroll
    for (int j = 0; j < 4; j++){ b0[j] = br[c0 + j]; b1[j] = br[c1 + j]; }
    #pragma unroll
    for (int i = 0; i < 4; i++){
      long r = r0 + tr + 32 * i;
      if (r < n){
        *reinterpret_cast<float4*>(&XR[r * 128 + c0]) =
          make_float4(acc[i][0] + b0[0], acc[i][1] + b0[1], acc[i][2] + b0[2], acc[i][3] + b0[3]);
        *reinterpret_cast<float4*>(&XR[r * 128 + c1]) =
          make_float4(acc[i][4] + b1[0], acc[i][5] + b1[1], acc[i][6] + b1[2], acc[i][7] + b1[3]);
      }
    }
  }
}

// ---------------- GATv2 edge phase (bf16 messages, predicated batch-8) ----------------
// One wave per dst node. Lane l owns channels cb, cb+1 of head (l>>4) packed in one uint.
// All edges run in uniform batch-8 iterations; invalid slots get logit -1e30 -> weight 0.
// Epilogue fuses /den, +bias, BN, leaky(0.1), +H. OUT may alias XR (own-row only).
__global__ void gat_edge_kernel(const uint* __restrict__ XLh, const float* __restrict__ XR,
                                const float* __restrict__ att, const float* __restrict__ bias,
                                const float* __restrict__ bn_g, const float* __restrict__ bn_b,
                                const float* __restrict__ bn_m, const float* __restrict__ bn_v,
                                const float* __restrict__ H, float* __restrict__ OUT,
                                const int* __restrict__ rowptr, const int* __restrict__ csr_src,
                                int n){
  int wid  = (int)((blockIdx.x * blockDim.x + threadIdx.x) >> 6);
  int lane = threadIdx.x & 63;
  if (wid >= n) return;
  const int d = wid;
  const int ch = ((lane >> 4) << 4) + (lane & 15);   // uint index in 64-uint row
  const int cb = ch << 1;                            // float channel base
  const float2 a2 = *reinterpret_cast<const float2*>(att + cb);
  const float2 xr = *reinterpret_cast<const float2*>(XR + (long)d * 128 + cb);
  uint ud = XLh[(long)d * 64 + ch];
  const float xd0 = __uint_as_float(ud << 16);
  const float xd1 = __uint_as_float(ud & 0xFFFF0000u);

  // self loop = initial state
  float m = dpp_add16(fmaf(a2.x, lrelu(xr.x + xd0, 0.2f), a2.y * lrelu(xr.y + xd1, 0.2f)));
  float den = 1.f;
  float O0 = xd0, O1 = xd1;

  const int start = rowptr[d], end = rowptr[d + 1];
  const int nb = (end - start + 7) >> 3;
  int eb = start;

  uint nxt[8];
  if (nb > 0){
    #pragma unroll
    for (int i = 0; i < 8; i++){
      int ec = eb + i; ec = ec < end ? ec : end - 1;
      nxt[i] = XLh[(long)csr_src[ec] * 64 + ch];
    }
  }
  for (int b = 0; b < nb; b++){
    uint cur[8];
    #pragma unroll
    for (int i = 0; i < 8; i++) cur[i] = nxt[i];
    if (b + 1 < nb){
      int ebn = eb + 8;
      #pragma unroll
      for (int i = 0; i < 8; i++){
        int ec = ebn + i; ec = ec < end ? ec : end - 1;
        nxt[i] = XLh[(long)csr_src[ec] * 64 + ch];
      }
    }
    float f0[8], f1[8], l[8];
    #pragma unroll
    for (int i = 0; i < 8; i++){
      f0[i] = __uint_as_float(cur[i] << 16);
      f1[i] = __uint_as_float(cur[i] & 0xFFFF0000u);
      float t = fmaf(a2.x, lrelu(xr.x + f0[i], 0.2f), a2.y * lrelu(xr.y + f1[i], 0.2f));
      float li = dpp_add16(t);
      l[i] = (eb + i < end) ? li : -1e30f;
    }
    float bm = fmaxf(fmaxf(fmaxf(l[0], l[1]), fmaxf(l[2], l[3])),
                     fmaxf(fmaxf(l[4], l[5]), fmaxf(l[6], l[7])));
    float nm = fmaxf(m, bm);
    float sc = __expf(m - nm);
    float ws = 0.f, ox = 0.f, oy = 0.f;
    #pragma unroll
    for (int i = 0; i < 8; i++){
      float w = __expf(l[i] - nm);
      ws += w;
      ox = fmaf(w, f0[i], ox);
      oy = fmaf(w, f1[i], oy);
    }
    den = fmaf(den, sc, ws);
    O0  = fmaf(O0, sc, ox);
    O1  = fmaf(O1, sc, oy);
    m = nm;
    eb += 8;
  }

  float inv = 1.f / (den + 1e-16f);
  float v0 = O0 * inv + bias[cb];
  float v1 = O1 * inv + bias[cb + 1];
  v0 = (v0 - bn_m[cb])     * rsqrtf(bn_v[cb]     + 1e-5f) * bn_g[cb]     + bn_b[cb];
  v1 = (v1 - bn_m[cb + 1]) * rsqrtf(bn_v[cb + 1] + 1e-5f) * bn_g[cb + 1] + bn_b[cb + 1];
  const float2 h2 = *reinterpret_cast<const float2*>(H + (long)d * 128 + cb);
  float2 res;
  res.x = lrelu(v0, 0.1f) + h2.x;
  res.y = lrelu(v1, 0.1f) + h2.y;
  *reinterpret_cast<float2*>(OUT + (long)d * 128 + cb) = res;
}

// ---------------- final 64->1 projection ----------------
__global__ void out2_kernel(const float* __restrict__ Hin, const float* __restrict__ Wo2,
                            const float* __restrict__ bo2, float* __restrict__ out, int n){
  int wid  = (int)((blockIdx.x * blockDim.x + threadIdx.x) >> 6);
  int lane = threadIdx.x & 63;
  if (wid >= n) return;
  float p = Hin[(long)wid * 64 + lane] * Wo2[lane];
  #pragma unroll
  for (int off = 1; off < 64; off <<= 1) p += __shfl_xor(p, off);
  if (lane == 0) out[wid] = p + bo2[0];
}

// ---------------- launch ----------------
extern "C" void kernel_launch(void* const* d_in, const int* in_sizes, int n_in,
                              void* d_out, int out_size, void* d_ws, size_t ws_size,
                              hipStream_t stream) {
  const float* x     = (const float*)d_in[0];
  const int*   ei    = (const int*)  d_in[1];
  const float* W_pre = (const float*)d_in[2];
  const float* b_pre = (const float*)d_in[3];
  const float* g_pre = (const float*)d_in[4];
  const float* be_pre= (const float*)d_in[5];
  const float* m_pre = (const float*)d_in[6];
  const float* v_pre = (const float*)d_in[7];
  const float* Wl1  = (const float*)d_in[8];
  const float* bl1  = (const float*)d_in[9];
  const float* Wr1  = (const float*)d_in[10];
  const float* br1  = (const float*)d_in[11];
  const float* att1 = (const float*)d_in[12];
  const float* bias1= (const float*)d_in[13];
  const float* g1   = (const float*)d_in[14];
  const float* be1  = (const float*)d_in[15];
  const float* m1   = (const float*)d_in[16];
  const float* v1   = (const float*)d_in[17];
  const float* Wl2  = (const float*)d_in[18];
  const float* bl2  = (const float*)d_in[19];
  const float* Wr2  = (const float*)d_in[20];
  const float* br2  = (const float*)d_in[21];
  const float* att2 = (const float*)d_in[22];
  const float* bias2= (const float*)d_in[23];
  const float* g2   = (const float*)d_in[24];
  const float* be2  = (const float*)d_in[25];
  const float* m2   = (const float*)d_in[26];
  const float* v2   = (const float*)d_in[27];
  const float* Wo1  = (const float*)d_in[28];
  const float* bo1  = (const float*)d_in[29];
  const float* Wo2  = (const float*)d_in[30];
  const float* bo2  = (const float*)d_in[31];
  float* out = (float*)d_out;
  char*  ws  = (char*)d_ws;

  float* buf0 = (float*)(ws + 0);           // [N,128] f32
  float* buf2 = (float*)(ws + 25600000);    // [N,128] f32
  uint*  hbuf = (uint*) (ws + 51200000);    // [N,64] packed bf16 pairs (12.8 MB)
  int* rowptr = (int*)(ws + 64000000);      // N+1
  int* deg    = (int*)(ws + 64200448);      // N (reused as scatter cursor)
  int* bsum   = (int*)(ws + 64400448);      // SCAN_B
  int* boff   = (int*)(ws + 64401472);      // SCAN_B
  int* csr    = (int*)(ws + 64600448);      // E (3.2 MB)
  int* flag   = (int*)(ws + 67800448);      // 1

  // CSR build (reused by both GAT layers)
  detect_kernel<<<1, 256, 0, stream>>>(ei, flag);
  zero1_kernel<<<SCAN_B, 256, 0, stream>>>(deg, NN);
  count_kernel<<<(EE + 255) / 256, 256, 0, stream>>>(ei, flag, deg);
  scan1_kernel<<<SCAN_B, 256, 0, stream>>>(deg, rowptr, bsum);
  scan2_kernel<<<1, 256, 0, stream>>>(bsum, boff, rowptr);
  scan3_kernel<<<SCAN_B, 256, 0, stream>>>(rowptr, boff, deg);
  scatter_kernel<<<(EE + 255) / 256, 256, 0, stream>>>(ei, flag, rowptr, deg, csr);

  const int GG = (NN + 127) / 128;
  const int GW = (NN + 3) / 4;

  // pre: buf0 = leaky(BN(x@W_pre + b_pre))
  gemm_kernel<64, 128, 1><<<GG, 512, 0, stream>>>(x, W_pre, b_pre, g_pre, be_pre, m_pre, v_pre, buf0, NN);
  // layer 1: hbuf = bf16(buf0@Wl1+bl1), buf2 = buf0@Wr1+br1
  dual_gemm_kernel<<<GG, 512, 0, stream>>>(buf0, Wl1, bl1, Wr1, br1, hbuf, buf2, NN);
  gat_edge_kernel<<<GW, 256, 0, stream>>>(hbuf, buf2, att1, bias1, g1, be1, m1, v1,
                                          buf0 /*H*/, buf2 /*OUT in-place*/, rowptr, csr, NN);
  // layer 2: hbuf = bf16(buf2@Wl2+bl2), buf0 = buf2@Wr2+br2
  dual_gemm_kernel<<<GG, 512, 0, stream>>>(buf2, Wl2, bl2, Wr2, br2, hbuf, buf0, NN);
  gat_edge_kernel<<<GW, 256, 0, stream>>>(hbuf, buf0, att2, bias2, g2, be2, m2, v2,
                                          buf2 /*H*/, buf0 /*OUT in-place*/, rowptr, csr, NN);
  // out head: buf2[:, :64] = leaky(buf0@Wo1+bo1); out = buf2@Wo2+bo2
  gemm_kernel<128, 64, 2><<<GG, 512, 0, stream>>>(buf0, Wo1, bo1, nullptr, nullptr, nullptr, nullptr, buf2, NN);
  out2_kernel<<<GW, 256, 0, stream>>>(buf2, Wo2, bo2, out, NN);
}